// Round 14
// baseline (85.918 us; speedup 1.0000x reference)
//
#include <hip/hip_runtime.h>

typedef __attribute__((ext_vector_type(8))) short short8;
typedef __attribute__((ext_vector_type(4))) short short4v;
typedef __attribute__((ext_vector_type(4))) float f32x4;
typedef __attribute__((ext_vector_type(2))) unsigned int uint2v;
typedef __attribute__((ext_vector_type(4))) unsigned int uint4v;

#define LOG2E 1.44269504088896340736f

__device__ __forceinline__ float fexp2(float v){ return __builtin_amdgcn_exp2f(v); }
__device__ __forceinline__ float frcp(float v){ return __builtin_amdgcn_rcpf(v); }
__device__ __forceinline__ float silu_f(float v){ return v * frcp(1.0f + fexp2(-v*LOG2E)); }
__device__ __forceinline__ float tanh_f(float v){ return 2.0f*frcp(1.0f+fexp2(-2.0f*LOG2E*v)) - 1.0f; }

__device__ __forceinline__ unsigned short f2bf(float f){
    unsigned int u = __float_as_uint(f);
    u = (u + 0x7FFFu + ((u>>16)&1u)) >> 16;
    return (unsigned short)u;
}
// v_cvt_pk_bf16_f32: lo16 = bf16(a), hi16 = bf16(b)
__device__ __forceinline__ unsigned int cvt_pk(float a, float b){
    unsigned int r;
    asm("v_cvt_pk_bf16_f32 %0, %1, %2" : "=v"(r) : "v"(a), "v"(b));
    return r;
}
__device__ __forceinline__ short4v mk4(unsigned int u0, unsigned int u1){
    uint2v t; t[0] = u0; t[1] = u1;
    return __builtin_bit_cast(short4v, t);
}
__device__ __forceinline__ short8 mk8(unsigned int a, unsigned int b, unsigned int c, unsigned int d){
    uint4v t; t[0] = a; t[1] = b; t[2] = c; t[3] = d;
    return __builtin_bit_cast(short8, t);
}
__device__ __forceinline__ short8 pack2x4(short4v lo, short4v hi){
    return __builtin_shufflevector(lo, hi, 0,1,2,3,4,5,6,7);
}
__device__ __forceinline__ short4v lo4(short8 v){ return __builtin_shufflevector(v, v, 0,1,2,3); }
__device__ __forceinline__ short4v hi4(short8 v){ return __builtin_shufflevector(v, v, 4,5,6,7); }

#define MFMA32(a,b,c) __builtin_amdgcn_mfma_f32_16x16x32_bf16(a,b,c,0,0,0)
#define MFMA16(a,b,c) __builtin_amdgcn_mfma_f32_16x16x16bf16_1k(a,b,c,0,0,0)

// Fragment layouts (validated rounds 2-13):
//  A frag: m=lane&15,  k = KW*(lane>>4)+e   (KW=8 for x32, 4 for x16)
//  B frag: n=lane&15,  k = KW*(lane>>4)+e
//  C frag: n=lane&15,  m = 4*(lane>>4)+r
// Layout tricks (R9): replicated gate A -> per-lane logits; final GEMM A at
//  m=8..10 -> MoE output lands at g==2 beside lin (stage1 concat f=40..42).
//
// R11-R14 structural rules:
//  - ALL block-uniform lane-dependent state in LDS; per-iteration zoff
//    (opaque zero) defeats LICM re-hoisting into registers (spill trigger,
//    R3/R4/R6/R10). Occupancy attributes requesting >=4 waves are
//    pathological (64-VGPR cap + spill) — do not reintroduce.
//  - R14: TWO sequential 16-row chains per iteration share one li ->
//    CSE serves both chains from one set of WF ds_reads; halves per-row
//    LDS issue + loop overhead; chain boundary gives scheduler overlap
//    (R7 measured -6.5% from boundary overlap alone).

__global__ __launch_bounds__(256)
void moe_mfma12_kernel(
    const float* __restrict__ x,
    const float* __restrict__ W1,  const float* __restrict__ b1,
    const float* __restrict__ lng, const float* __restrict__ lnb,
    const float* __restrict__ W2,  const float* __restrict__ b2,
    const float* __restrict__ Wg1, const float* __restrict__ bg1,
    const float* __restrict__ Wg2, const float* __restrict__ bg2,
    const float* __restrict__ We1, const float* __restrict__ be1,
    const float* __restrict__ We2, const float* __restrict__ be2,
    const float* __restrict__ Wh,  const float* __restrict__ bh,
    const float* __restrict__ osc,
    float* __restrict__ out, int B, int niter)
{
    const int tid  = threadIdx.x;
    const int w    = tid >> 6;
    const int lane = tid & 63;
    const int c    = lane & 15;   // batch row within group / A-row m
    const int g    = lane >> 4;   // lane group 0..3

    __shared__ short8 WF[14][64];   // weight fragments, 16B/lane/slot
    __shared__ f32x4  BS[3][64];    // stage1 C-init biases
    __shared__ uint2v AG[64];       // gate A fragment (8B/lane)

    const int stride = (int)gridDim.x * 128;          // 4 waves x 32 rows
    int rowA = (int)blockIdx.x * 128 + w * 32;        // chain A base; B = +16

    // ---- prefetch iter 0 for both chains ----
    f32x4 pa0, pa1, pa2, pa3, pb0, pb1, pb2, pb3;
    {
        int rA = rowA + c;      if (rA >= B) rA = B - 1; if (rA < 0) rA = 0;
        int rB = rowA + 16 + c; if (rB >= B) rB = B - 1; if (rB < 0) rB = 0;
        const float* npA = x + (size_t)rA * 64 + 8 * g;
        const float* npB = x + (size_t)rB * 64 + 8 * g;
        pa0 = *(const f32x4*)(npA);      pb0 = *(const f32x4*)(npB);
        pa1 = *(const f32x4*)(npA + 4);  pb1 = *(const f32x4*)(npB + 4);
        pa2 = *(const f32x4*)(npA + 32); pb2 = *(const f32x4*)(npB + 32);
        pa3 = *(const f32x4*)(npA + 36); pb3 = *(const f32x4*)(npB + 36);
    }

    // ================= wave 0 stages all block-uniform state into LDS =================
    if (w == 0) {
        // stage1 concat features f: [0,24)=W1, [24,40)=Wg1, [40,43)=Wh, pad 48
#pragma unroll
        for (int t = 0; t < 3; ++t) {
            const int f = 16 * t + c;
#pragma unroll
            for (int s = 0; s < 2; ++s) {
                short8 r;
#pragma unroll
                for (int e = 0; e < 8; ++e) {
                    const int k = 32 * s + 8 * g + e;
                    float v = 0.0f;
                    if (f < 24)      v = W1[k * 24 + f];
                    else if (f < 40) v = Wg1[k * 16 + (f - 24)];
                    else if (f < 43) v = Wh[k * 3 + (f - 40)];
                    r[e] = (short)f2bf(v);
                }
                WF[t * 2 + s][lane] = r;
            }
        }
        // W2 (lng folded), K=24 pad 32; b2' (lnb fold) in k==24 slot
#pragma unroll
        for (int t = 0; t < 2; ++t) {
            const int f = 16 * t + c;
            float bfold = 0.0f;
            if (f < 24) {
                bfold = b2[f];
                for (int k = 0; k < 24; ++k) bfold += lnb[k] * W2[k * 24 + f];
            }
            short4v h[2];
#pragma unroll
            for (int s = 0; s < 2; ++s) {
                short4v r;
#pragma unroll
                for (int e = 0; e < 4; ++e) {
                    const int k = 16 * s + 4 * g + e;
                    float v = (f < 24 && k < 24) ? lng[k] * W2[k * 24 + f] : 0.0f;
                    if (s == 1 && g == 2 && e == 0) v = bfold;
                    r[e] = (short)f2bf(v);
                }
                h[s] = r;
            }
            WF[6 + t][lane] = pack2x4(h[0], h[1]);
        }
        // experts hidden concat m in [0,60), K=24 pad 32; be1 in k==24 slot
#pragma unroll
        for (int t = 0; t < 4; ++t) {
            const int f  = 16 * t + c;
            const int fc = (f < 60) ? f : 0;
            const int ei = fc / 20, j = fc % 20;
            const float bias = (f < 60) ? be1[f] : 0.0f;
            short4v h[2];
#pragma unroll
            for (int s = 0; s < 2; ++s) {
                short4v r;
#pragma unroll
                for (int e = 0; e < 4; ++e) {
                    const int k = 16 * s + 4 * g + e;
                    float v = (f < 60 && k < 24) ? We1[(ei * 24 + k) * 20 + j] : 0.0f;
                    if (s == 1 && g == 2 && e == 0) v = bias;
                    r[e] = (short)f2bf(v);
                }
                h[s] = r;
            }
            WF[8 + t][lane] = pack2x4(h[0], h[1]);
        }
        // final GEMM A at rows m=8..10 (o=c-8): We2*osc, be2*osc in k=60..62
        {
            const int  o     = c - 8;
            const bool valid = (c >= 8 && c < 11);
            const int  oc    = valid ? o : 0;
            const float oscv = valid ? osc[oc] : 0.0f;
            short4v h[4];
#pragma unroll
            for (int s = 0; s < 4; ++s) {
                short4v r;
#pragma unroll
                for (int e = 0; e < 4; ++e) {
                    const int k = 16 * s + 4 * g + e;
                    float v = 0.0f;
                    if (valid) {
                        if (k < 60) {
                            const int ei = k / 20, j = k % 20;
                            v = We2[(ei * 20 + j) * 3 + oc] * oscv;
                        } else if (k < 63) {
                            v = be2[(k - 60) * 3 + oc] * oscv;
                        }
                    }
                    r[e] = (short)f2bf(v);
                }
                h[s] = r;
            }
            WF[12][lane] = pack2x4(h[0], h[1]);
            WF[13][lane] = pack2x4(h[2], h[3]);
        }
        // stage1 biases
#pragma unroll
        for (int t = 0; t < 3; ++t) {
            f32x4 bv;
#pragma unroll
            for (int r = 0; r < 4; ++r) {
                const int m = 16 * t + 4 * g + r;
                float v = 0.0f;
                if (m < 24)      v = b1[m];
                else if (m < 40) v = bg1[m - 24];
                else if (m < 43) v = bh[m - 40];
                bv[r] = v;
            }
            BS[t][lane] = bv;
        }
        // gate Wg2 replicated across row-groups: row m holds Wg2[:, m%4]
        {
            const int og = c & 3;
            short4v r;
#pragma unroll
            for (int e = 0; e < 4; ++e) {
                const int k = 4 * g + e;
                float v = (og < 3) ? Wg2[k * 3 + og] : 0.0f;
                r[e] = (short)f2bf(v);
            }
            AG[lane] = __builtin_bit_cast(uint2v, r);
        }
    }

    const float gb0 = bg2[0], gb1 = bg2[1], gb2 = bg2[2];
    const unsigned int ONEBF = 0x00003F80u;  // lo half = bf16(1.0)

    __syncthreads();   // LDS ready; read-only hereafter (no barriers in loop)

    // ================= main loop: two sequential 16-row chains per iter =================
    for (int it = 0; it < niter; ++it) {
        if (rowA >= B) break;

        // opaque zero: LDS addresses loop-variant -> no cross-iter LICM;
        // within the iteration both chains share li -> CSE merges WF reads.
        int zoff = 0;
        asm volatile("" : "+v"(zoff));
        const int li = lane + zoff;

        const int cur  = rowA;
        const int nrow = rowA + stride;

        const f32x4 qa0 = pa0, qa1 = pa1, qa2 = pa2, qa3 = pa3;
        const f32x4 qb0 = pb0, qb1 = pb1, qb2 = pb2, qb3 = pb3;
        if (it + 1 < niter && nrow < B) {
            int rA = nrow + c;      if (rA >= B) rA = B - 1;
            int rB = nrow + 16 + c; if (rB >= B) rB = B - 1;
            const float* npA = x + (size_t)rA * 64 + 8 * g;
            const float* npB = x + (size_t)rB * 64 + 8 * g;
            pa0 = *(const f32x4*)(npA);      pb0 = *(const f32x4*)(npB);
            pa1 = *(const f32x4*)(npA + 4);  pb1 = *(const f32x4*)(npB + 4);
            pa2 = *(const f32x4*)(npA + 32); pb2 = *(const f32x4*)(npB + 32);
            pa3 = *(const f32x4*)(npA + 36); pb3 = *(const f32x4*)(npB + 36);
        }

        auto process = [&](int prow, const f32x4& q0, const f32x4& q1,
                           const f32x4& q2, const f32x4& q3) {
            // x -> bf16 B fragments
            const short8 bx0 = mk8(cvt_pk(q0[0],q0[1]), cvt_pk(q0[2],q0[3]),
                                   cvt_pk(q1[0],q1[1]), cvt_pk(q1[2],q1[3]));
            const short8 bx1 = mk8(cvt_pk(q2[0],q2[1]), cvt_pk(q2[2],q2[3]),
                                   cvt_pk(q3[0],q3[1]), cvt_pk(q3[2],q3[3]));

            // stage 1: 3 M-tiles x K=64 (A frags + biases from LDS)
            const short8 A100 = WF[0][li], A101 = WF[1][li];
            const short8 A110 = WF[2][li], A111 = WF[3][li];
            const short8 A120 = WF[4][li], A121 = WF[5][li];
            f32x4 c0 = BS[0][li];
            f32x4 c1 = BS[1][li];
            f32x4 c2 = BS[2][li];
            c0 = MFMA32(A100, bx0, c0); c0 = MFMA32(A101, bx1, c0);
            c1 = MFMA32(A110, bx0, c1); c1 = MFMA32(A111, bx1, c1);
            c2 = MFMA32(A120, bx0, c2); c2 = MFMA32(A121, bx1, c2);

            // gate: tanh + lane^32 exchange; replicated-A -> per-lane logits
            const f32x4 ts = (g < 2) ? c2 : c1;
            const unsigned int gs0 = cvt_pk(tanh_f(ts[0]), tanh_f(ts[1]));
            const unsigned int gs1 = cvt_pk(tanh_f(ts[2]), tanh_f(ts[3]));
            const unsigned int gr0 = (unsigned int)__shfl_xor((int)gs0, 32, 64);
            const unsigned int gr1 = (unsigned int)__shfl_xor((int)gs1, 32, 64);
            const short4v ag = __builtin_bit_cast(short4v, AG[li]);
            f32x4 cg = { gb0, gb1, gb2, 0.0f };
            cg = MFMA16(ag, mk4(gr0, gr1), cg);

            // silu + LayerNorm (lng/lnb folded into W2 frags)
            const float h00=silu_f(c0[0]), h01=silu_f(c0[1]), h02=silu_f(c0[2]), h03=silu_f(c0[3]);
            const float h10=silu_f(c1[0]), h11=silu_f(c1[1]), h12=silu_f(c1[2]), h13=silu_f(c1[3]);
            float S = h00+h01+h02+h03;
            float Q = h00*h00+h01*h01+h02*h02+h03*h03;
            if (g < 2) { S += h10+h11+h12+h13; Q += h10*h10+h11*h11+h12*h12+h13*h13; }
            S += __shfl_xor(S, 16, 64); S += __shfl_xor(S, 32, 64);
            Q += __shfl_xor(Q, 16, 64); Q += __shfl_xor(Q, 32, 64);
            const float mu = S * (1.0f/24.0f);
            float var = Q * (1.0f/24.0f) - mu*mu; var = fmaxf(var, 0.0f);
            const float inv = __builtin_amdgcn_rsqf(var + 1e-5f);

            const short4v B0 = mk4(cvt_pk((h00-mu)*inv, (h01-mu)*inv),
                                   cvt_pk((h02-mu)*inv, (h03-mu)*inv));
            const short4v B1 = (g < 2) ? mk4(cvt_pk((h10-mu)*inv, (h11-mu)*inv),
                                             cvt_pk((h12-mu)*inv, (h13-mu)*inv))
                             : ((g == 2) ? mk4(ONEBF, 0u) : mk4(0u, 0u));

            // stage 2 (A frags from LDS; bias rides k==24 slot)
            const short8 AWp0 = WF[6][li], AWp1 = WF[7][li];
            f32x4 d0 = {0.f,0.f,0.f,0.f}, d1 = {0.f,0.f,0.f,0.f};
            d0 = MFMA16(lo4(AWp0), B0, d0); d0 = MFMA16(hi4(AWp0), B1, d0);
            d1 = MFMA16(lo4(AWp1), B0, d1); d1 = MFMA16(hi4(AWp1), B1, d1);
            const float j00=silu_f(d0[0]), j01=silu_f(d0[1]), j02=silu_f(d0[2]), j03=silu_f(d0[3]);
            const float j10=silu_f(d1[0]), j11=silu_f(d1[1]), j12=silu_f(d1[2]), j13=silu_f(d1[3]);
            const short4v E0 = mk4(cvt_pk(j00,j01), cvt_pk(j02,j03));
            const short4v E1 = (g < 2) ? mk4(cvt_pk(j10,j11), cvt_pk(j12,j13))
                             : ((g == 2) ? mk4(ONEBF, 0u) : mk4(0u, 0u));

            // experts hidden: 60-feature concat, 4 M-tiles
            const short8 AEp0 = WF[8][li],  AEp1 = WF[9][li];
            const short8 AEp2 = WF[10][li], AEp3 = WF[11][li];
            f32x4 e0={0.f,0.f,0.f,0.f}, e1={0.f,0.f,0.f,0.f};
            f32x4 e2={0.f,0.f,0.f,0.f}, e3={0.f,0.f,0.f,0.f};
            e0 = MFMA16(lo4(AEp0), E0, e0); e0 = MFMA16(hi4(AEp0), E1, e0);
            e1 = MFMA16(lo4(AEp1), E0, e1); e1 = MFMA16(hi4(AEp1), E1, e1);
            e2 = MFMA16(lo4(AEp2), E0, e2); e2 = MFMA16(hi4(AEp2), E1, e2);
            e3 = MFMA16(lo4(AEp3), E0, e3); e3 = MFMA16(hi4(AEp3), E1, e3);

            // softmax gate weights (per-lane logits; tanh-bounded)
            const float x0 = fexp2(cg[0]*LOG2E), x1 = fexp2(cg[1]*LOG2E), x2 = fexp2(cg[2]*LOG2E);
            const float rs = frcp(x0 + x1 + x2);
            const float gw0 = x0*rs, gw1 = x1*rs, gw2 = x2*rs;

            // final GEMM: B = gw[expert(k)]*silu(eh[k]) (k<60), gw vec in pads
            const float gt0 = gw0;
            const float gt1 = (g == 0) ? gw0 : gw1;
            const float gt2 = (g < 2) ? gw1 : gw2;
            const float gt3 = gw2;
            const short4v F0 = mk4(cvt_pk(gt0*silu_f(e0[0]), gt0*silu_f(e0[1])),
                                   cvt_pk(gt0*silu_f(e0[2]), gt0*silu_f(e0[3])));
            const short4v F1 = mk4(cvt_pk(gt1*silu_f(e1[0]), gt1*silu_f(e1[1])),
                                   cvt_pk(gt1*silu_f(e1[2]), gt1*silu_f(e1[3])));
            const short4v F2 = mk4(cvt_pk(gt2*silu_f(e2[0]), gt2*silu_f(e2[1])),
                                   cvt_pk(gt2*silu_f(e2[2]), gt2*silu_f(e2[3])));
            const short4v F3 = (g == 3) ? mk4(cvt_pk(gw0, gw1), cvt_pk(gw2, 0.0f))
                             : mk4(cvt_pk(gt3*silu_f(e3[0]), gt3*silu_f(e3[1])),
                                   cvt_pk(gt3*silu_f(e3[2]), gt3*silu_f(e3[3])));
            const short8 AOp0 = WF[12][li], AOp1 = WF[13][li];
            f32x4 co = {0.f,0.f,0.f,0.f};
            co = MFMA16(lo4(AOp0), F0, co); co = MFMA16(hi4(AOp0), F1, co);
            co = MFMA16(lo4(AOp1), F2, co); co = MFMA16(hi4(AOp1), F3, co);

            // lin lives in c2[0..2] at g==2; moe output lands there too
            if (g == 2 && prow + c < B) {
                float* op = out + (size_t)(prow + c) * 3;
                op[0] = c2[0] + co[0];
                op[1] = c2[1] + co[1];
                op[2] = c2[2] + co[2];
            }
        };

        process(cur, qa0, qa1, qa2, qa3);
        if (cur + 16 < B) process(cur + 16, qb0, qb1, qb2, qb3);

        rowA = nrow;
    }
}

extern "C" void kernel_launch(void* const* d_in, const int* in_sizes, int n_in,
                              void* d_out, int out_size, void* d_ws, size_t ws_size,
                              hipStream_t stream) {
    const float* x   = (const float*)d_in[0];
    const float* W1  = (const float*)d_in[1];
    const float* b1  = (const float*)d_in[2];
    const float* lng = (const float*)d_in[3];
    const float* lnb = (const float*)d_in[4];
    const float* W2  = (const float*)d_in[5];
    const float* b2  = (const float*)d_in[6];
    const float* Wg1 = (const float*)d_in[7];
    const float* bg1 = (const float*)d_in[8];
    const float* Wg2 = (const float*)d_in[9];
    const float* bg2 = (const float*)d_in[10];
    const float* We1 = (const float*)d_in[11];
    const float* be1 = (const float*)d_in[12];
    const float* We2 = (const float*)d_in[13];
    const float* be2 = (const float*)d_in[14];
    const float* Wh  = (const float*)d_in[15];
    const float* bh  = (const float*)d_in[16];
    const float* osc = (const float*)d_in[17];
    float* out = (float*)d_out;

    const int B = in_sizes[0] / 64;
    const int G = 2048;                        // 8 blocks/CU target
    const long long per = (long long)G * 128;  // 128 rows/block/iter
    const int niter = (int)((B + per - 1) / per);
    moe_mfma12_kernel<<<dim3(G), dim3(256), 0, stream>>>(
        x, W1, b1, lng, lnb, W2, b2, Wg1, bg1, Wg2, bg2,
        We1, be1, We2, be2, Wh, bh, osc, out, B, niter);
}

// Round 15
// 72.286 us; speedup vs baseline: 1.1886x; 1.1886x over previous
//
#include <hip/hip_runtime.h>

typedef __attribute__((ext_vector_type(8))) short short8;
typedef __attribute__((ext_vector_type(4))) short short4v;
typedef __attribute__((ext_vector_type(4))) float f32x4;
typedef __attribute__((ext_vector_type(2))) unsigned int uint2v;
typedef __attribute__((ext_vector_type(4))) unsigned int uint4v;

#define LOG2E 1.44269504088896340736f

__device__ __forceinline__ float fexp2(float v){ return __builtin_amdgcn_exp2f(v); }
__device__ __forceinline__ float frcp(float v){ return __builtin_amdgcn_rcpf(v); }
__device__ __forceinline__ float silu_f(float v){ return v * frcp(1.0f + fexp2(-v*LOG2E)); }
__device__ __forceinline__ float tanh_f(float v){ return 2.0f*frcp(1.0f+fexp2(-2.0f*LOG2E*v)) - 1.0f; }

__device__ __forceinline__ unsigned short f2bf(float f){
    unsigned int u = __float_as_uint(f);
    u = (u + 0x7FFFu + ((u>>16)&1u)) >> 16;
    return (unsigned short)u;
}
// v_cvt_pk_bf16_f32: lo16 = bf16(a), hi16 = bf16(b)
__device__ __forceinline__ unsigned int cvt_pk(float a, float b){
    unsigned int r;
    asm("v_cvt_pk_bf16_f32 %0, %1, %2" : "=v"(r) : "v"(a), "v"(b));
    return r;
}
__device__ __forceinline__ short4v mk4(unsigned int u0, unsigned int u1){
    uint2v t; t[0] = u0; t[1] = u1;
    return __builtin_bit_cast(short4v, t);
}
__device__ __forceinline__ short8 mk8(unsigned int a, unsigned int b, unsigned int c, unsigned int d){
    uint4v t; t[0] = a; t[1] = b; t[2] = c; t[3] = d;
    return __builtin_bit_cast(short8, t);
}
__device__ __forceinline__ short8 pack2x4(short4v lo, short4v hi){
    return __builtin_shufflevector(lo, hi, 0,1,2,3,4,5,6,7);
}
__device__ __forceinline__ short4v lo4(short8 v){ return __builtin_shufflevector(v, v, 0,1,2,3); }
__device__ __forceinline__ short4v hi4(short8 v){ return __builtin_shufflevector(v, v, 4,5,6,7); }

#define MFMA32(a,b,c) __builtin_amdgcn_mfma_f32_16x16x32_bf16(a,b,c,0,0,0)
#define MFMA16(a,b,c) __builtin_amdgcn_mfma_f32_16x16x16bf16_1k(a,b,c,0,0,0)

// Fragment layouts (validated rounds 2-14):
//  A frag: m=lane&15,  k = KW*(lane>>4)+e   (KW=8 for x32, 4 for x16)
//  B frag: n=lane&15,  k = KW*(lane>>4)+e
//  C frag: n=lane&15,  m = 4*(lane>>4)+r
// Layout tricks (R9): replicated gate A -> per-lane logits; final GEMM A at
//  m=8..10 -> MoE output lands at g==2 beside lin (stage1 concat f=40..42).
//
// R11-R15 structural rules:
//  - ALL block-uniform lane-dependent state in LDS; per-iteration zoff
//    (opaque zero) defeats LICM re-hoisting into registers (spill trigger).
//  - Occupancy: MIN-hints >=4 on a register-heavy body are pathological
//    (R6/R10: 64-VGPR cap + spill). With the LDS-lean body (honest ~85
//    VGPR), waves_per_eu(5,5) pins budget 102 >= 85 -> 5 waves/EU
//    guaranteed, no squeeze (same min==max precedent as (2,2)/(3,3)).
//  - R12/R14 lessons: register diet alone and two-chain sharing are FLAT;
//    the plateau is contexts or chain latency, so pin contexts explicitly.

__global__ __launch_bounds__(256)
__attribute__((amdgpu_waves_per_eu(5, 5)))
void moe_mfma13_kernel(
    const float* __restrict__ x,
    const float* __restrict__ W1,  const float* __restrict__ b1,
    const float* __restrict__ lng, const float* __restrict__ lnb,
    const float* __restrict__ W2,  const float* __restrict__ b2,
    const float* __restrict__ Wg1, const float* __restrict__ bg1,
    const float* __restrict__ Wg2, const float* __restrict__ bg2,
    const float* __restrict__ We1, const float* __restrict__ be1,
    const float* __restrict__ We2, const float* __restrict__ be2,
    const float* __restrict__ Wh,  const float* __restrict__ bh,
    const float* __restrict__ osc,
    float* __restrict__ out, int B, int niter)
{
    const int tid  = threadIdx.x;
    const int w    = tid >> 6;
    const int lane = tid & 63;
    const int c    = lane & 15;   // batch row within group / A-row m
    const int g    = lane >> 4;   // lane group 0..3

    __shared__ short8 WF[14][64];   // weight fragments, 16B/lane/slot
    __shared__ f32x4  BS[3][64];    // stage1 C-init biases
    __shared__ uint2v AG[64];       // gate A fragment (8B/lane)

    const int stride = (int)gridDim.x * 64;          // 4 waves x 16 rows
    int row0 = (int)blockIdx.x * 64 + w * 16;

    // ---- prefetch iter 0 ----
    f32x4 pf0, pf1, pf2, pf3;
    {
        int r = row0 + c; if (r >= B) r = B - 1; if (r < 0) r = 0;
        const float* xp = x + (size_t)r * 64 + 8 * g;
        pf0 = *(const f32x4*)(xp);
        pf1 = *(const f32x4*)(xp + 4);
        pf2 = *(const f32x4*)(xp + 32);
        pf3 = *(const f32x4*)(xp + 36);
    }

    // ================= wave 0 stages all block-uniform state into LDS =================
    if (w == 0) {
        // stage1 concat features f: [0,24)=W1, [24,40)=Wg1, [40,43)=Wh, pad 48
#pragma unroll
        for (int t = 0; t < 3; ++t) {
            const int f = 16 * t + c;
#pragma unroll
            for (int s = 0; s < 2; ++s) {
                short8 r;
#pragma unroll
                for (int e = 0; e < 8; ++e) {
                    const int k = 32 * s + 8 * g + e;
                    float v = 0.0f;
                    if (f < 24)      v = W1[k * 24 + f];
                    else if (f < 40) v = Wg1[k * 16 + (f - 24)];
                    else if (f < 43) v = Wh[k * 3 + (f - 40)];
                    r[e] = (short)f2bf(v);
                }
                WF[t * 2 + s][lane] = r;
            }
        }
        // W2 (lng folded), K=24 pad 32; b2' (lnb fold) in k==24 slot
#pragma unroll
        for (int t = 0; t < 2; ++t) {
            const int f = 16 * t + c;
            float bfold = 0.0f;
            if (f < 24) {
                bfold = b2[f];
                for (int k = 0; k < 24; ++k) bfold += lnb[k] * W2[k * 24 + f];
            }
            short4v h[2];
#pragma unroll
            for (int s = 0; s < 2; ++s) {
                short4v r;
#pragma unroll
                for (int e = 0; e < 4; ++e) {
                    const int k = 16 * s + 4 * g + e;
                    float v = (f < 24 && k < 24) ? lng[k] * W2[k * 24 + f] : 0.0f;
                    if (s == 1 && g == 2 && e == 0) v = bfold;
                    r[e] = (short)f2bf(v);
                }
                h[s] = r;
            }
            WF[6 + t][lane] = pack2x4(h[0], h[1]);
        }
        // experts hidden concat m in [0,60), K=24 pad 32; be1 in k==24 slot
#pragma unroll
        for (int t = 0; t < 4; ++t) {
            const int f  = 16 * t + c;
            const int fc = (f < 60) ? f : 0;
            const int ei = fc / 20, j = fc % 20;
            const float bias = (f < 60) ? be1[f] : 0.0f;
            short4v h[2];
#pragma unroll
            for (int s = 0; s < 2; ++s) {
                short4v r;
#pragma unroll
                for (int e = 0; e < 4; ++e) {
                    const int k = 16 * s + 4 * g + e;
                    float v = (f < 60 && k < 24) ? We1[(ei * 24 + k) * 20 + j] : 0.0f;
                    if (s == 1 && g == 2 && e == 0) v = bias;
                    r[e] = (short)f2bf(v);
                }
                h[s] = r;
            }
            WF[8 + t][lane] = pack2x4(h[0], h[1]);
        }
        // final GEMM A at rows m=8..10 (o=c-8): We2*osc, be2*osc in k=60..62
        {
            const int  o     = c - 8;
            const bool valid = (c >= 8 && c < 11);
            const int  oc    = valid ? o : 0;
            const float oscv = valid ? osc[oc] : 0.0f;
            short4v h[4];
#pragma unroll
            for (int s = 0; s < 4; ++s) {
                short4v r;
#pragma unroll
                for (int e = 0; e < 4; ++e) {
                    const int k = 16 * s + 4 * g + e;
                    float v = 0.0f;
                    if (valid) {
                        if (k < 60) {
                            const int ei = k / 20, j = k % 20;
                            v = We2[(ei * 20 + j) * 3 + oc] * oscv;
                        } else if (k < 63) {
                            v = be2[(k - 60) * 3 + oc] * oscv;
                        }
                    }
                    r[e] = (short)f2bf(v);
                }
                h[s] = r;
            }
            WF[12][lane] = pack2x4(h[0], h[1]);
            WF[13][lane] = pack2x4(h[2], h[3]);
        }
        // stage1 biases
#pragma unroll
        for (int t = 0; t < 3; ++t) {
            f32x4 bv;
#pragma unroll
            for (int r = 0; r < 4; ++r) {
                const int m = 16 * t + 4 * g + r;
                float v = 0.0f;
                if (m < 24)      v = b1[m];
                else if (m < 40) v = bg1[m - 24];
                else if (m < 43) v = bh[m - 40];
                bv[r] = v;
            }
            BS[t][lane] = bv;
        }
        // gate Wg2 replicated across row-groups: row m holds Wg2[:, m%4]
        {
            const int og = c & 3;
            short4v r;
#pragma unroll
            for (int e = 0; e < 4; ++e) {
                const int k = 4 * g + e;
                float v = (og < 3) ? Wg2[k * 3 + og] : 0.0f;
                r[e] = (short)f2bf(v);
            }
            AG[lane] = __builtin_bit_cast(uint2v, r);
        }
    }

    const float gb0 = bg2[0], gb1 = bg2[1], gb2 = bg2[2];
    const unsigned int ONEBF = 0x00003F80u;  // lo half = bf16(1.0)

    __syncthreads();   // LDS ready; read-only hereafter (no barriers in loop)

    // ================= main loop: one 16-row chain per wave per iter =================
    for (int it = 0; it < niter; ++it) {
        if (row0 >= B) break;

        // opaque zero: LDS addresses become loop-variant -> no LICM re-hoist
        int zoff = 0;
        asm volatile("" : "+v"(zoff));
        const int li = lane + zoff;

        // ---- x -> bf16 B fragments (consumes pf before reloading it) ----
        const short8 bx0 = mk8(cvt_pk(pf0[0],pf0[1]), cvt_pk(pf0[2],pf0[3]),
                               cvt_pk(pf1[0],pf1[1]), cvt_pk(pf1[2],pf1[3]));
        const short8 bx1 = mk8(cvt_pk(pf2[0],pf2[1]), cvt_pk(pf2[2],pf2[3]),
                               cvt_pk(pf3[0],pf3[1]), cvt_pk(pf3[2],pf3[3]));

        const int cur  = row0;
        const int nrow = row0 + stride;
        if (it + 1 < niter && nrow < B) {
            int r = nrow + c; if (r >= B) r = B - 1;
            const float* np = x + (size_t)r * 64 + 8 * g;
            pf0 = *(const f32x4*)(np);
            pf1 = *(const f32x4*)(np + 4);
            pf2 = *(const f32x4*)(np + 32);
            pf3 = *(const f32x4*)(np + 36);
        }

        // ---- stage 1: 3 M-tiles x K=64 (A frags + biases from LDS) ----
        const short8 A100 = WF[0][li], A101 = WF[1][li];
        const short8 A110 = WF[2][li], A111 = WF[3][li];
        const short8 A120 = WF[4][li], A121 = WF[5][li];
        f32x4 c0 = BS[0][li];
        f32x4 c1 = BS[1][li];
        f32x4 c2 = BS[2][li];
        c0 = MFMA32(A100, bx0, c0); c0 = MFMA32(A101, bx1, c0);
        c1 = MFMA32(A110, bx0, c1); c1 = MFMA32(A111, bx1, c1);
        c2 = MFMA32(A120, bx0, c2); c2 = MFMA32(A121, bx1, c2);

        // ---- gate: tanh + lane^32 exchange; replicated-A -> per-lane logits ----
        const f32x4 ts = (g < 2) ? c2 : c1;
        const unsigned int gs0 = cvt_pk(tanh_f(ts[0]), tanh_f(ts[1]));
        const unsigned int gs1 = cvt_pk(tanh_f(ts[2]), tanh_f(ts[3]));
        const unsigned int gr0 = (unsigned int)__shfl_xor((int)gs0, 32, 64);
        const unsigned int gr1 = (unsigned int)__shfl_xor((int)gs1, 32, 64);
        const short4v ag = __builtin_bit_cast(short4v, AG[li]);
        f32x4 cg = { gb0, gb1, gb2, 0.0f };
        cg = MFMA16(ag, mk4(gr0, gr1), cg);

        // ---- silu + LayerNorm (lng/lnb folded into W2 frags) ----
        const float h00=silu_f(c0[0]), h01=silu_f(c0[1]), h02=silu_f(c0[2]), h03=silu_f(c0[3]);
        const float h10=silu_f(c1[0]), h11=silu_f(c1[1]), h12=silu_f(c1[2]), h13=silu_f(c1[3]);
        float S = h00+h01+h02+h03;
        float Q = h00*h00+h01*h01+h02*h02+h03*h03;
        if (g < 2) { S += h10+h11+h12+h13; Q += h10*h10+h11*h11+h12*h12+h13*h13; }
        S += __shfl_xor(S, 16, 64); S += __shfl_xor(S, 32, 64);
        Q += __shfl_xor(Q, 16, 64); Q += __shfl_xor(Q, 32, 64);
        const float mu = S * (1.0f/24.0f);
        float var = Q * (1.0f/24.0f) - mu*mu; var = fmaxf(var, 0.0f);
        const float inv = __builtin_amdgcn_rsqf(var + 1e-5f);

        const short4v B0 = mk4(cvt_pk((h00-mu)*inv, (h01-mu)*inv),
                               cvt_pk((h02-mu)*inv, (h03-mu)*inv));
        const short4v B1 = (g < 2) ? mk4(cvt_pk((h10-mu)*inv, (h11-mu)*inv),
                                         cvt_pk((h12-mu)*inv, (h13-mu)*inv))
                         : ((g == 2) ? mk4(ONEBF, 0u) : mk4(0u, 0u));

        // ---- stage 2 (A frags from LDS; bias rides k==24 slot) ----
        const short8 AWp0 = WF[6][li], AWp1 = WF[7][li];
        f32x4 d0 = {0.f,0.f,0.f,0.f}, d1 = {0.f,0.f,0.f,0.f};
        d0 = MFMA16(lo4(AWp0), B0, d0); d0 = MFMA16(hi4(AWp0), B1, d0);
        d1 = MFMA16(lo4(AWp1), B0, d1); d1 = MFMA16(hi4(AWp1), B1, d1);
        const float j00=silu_f(d0[0]), j01=silu_f(d0[1]), j02=silu_f(d0[2]), j03=silu_f(d0[3]);
        const float j10=silu_f(d1[0]), j11=silu_f(d1[1]), j12=silu_f(d1[2]), j13=silu_f(d1[3]);
        const short4v E0 = mk4(cvt_pk(j00,j01), cvt_pk(j02,j03));
        const short4v E1 = (g < 2) ? mk4(cvt_pk(j10,j11), cvt_pk(j12,j13))
                         : ((g == 2) ? mk4(ONEBF, 0u) : mk4(0u, 0u));

        // ---- experts hidden: 60-feature concat, 4 M-tiles ----
        const short8 AEp0 = WF[8][li],  AEp1 = WF[9][li];
        const short8 AEp2 = WF[10][li], AEp3 = WF[11][li];
        f32x4 e0={0.f,0.f,0.f,0.f}, e1={0.f,0.f,0.f,0.f};
        f32x4 e2={0.f,0.f,0.f,0.f}, e3={0.f,0.f,0.f,0.f};
        e0 = MFMA16(lo4(AEp0), E0, e0); e0 = MFMA16(hi4(AEp0), E1, e0);
        e1 = MFMA16(lo4(AEp1), E0, e1); e1 = MFMA16(hi4(AEp1), E1, e1);
        e2 = MFMA16(lo4(AEp2), E0, e2); e2 = MFMA16(hi4(AEp2), E1, e2);
        e3 = MFMA16(lo4(AEp3), E0, e3); e3 = MFMA16(hi4(AEp3), E1, e3);

        // ---- softmax gate weights (per-lane logits; tanh-bounded, no max-sub) ----
        const float x0 = fexp2(cg[0]*LOG2E), x1 = fexp2(cg[1]*LOG2E), x2 = fexp2(cg[2]*LOG2E);
        const float rs = frcp(x0 + x1 + x2);
        const float gw0 = x0*rs, gw1 = x1*rs, gw2 = x2*rs;

        // ---- final GEMM: B = gw[expert(k)]*silu(eh[k]) (k<60), gw vec in pads ----
        const float gt0 = gw0;
        const float gt1 = (g == 0) ? gw0 : gw1;
        const float gt2 = (g < 2) ? gw1 : gw2;
        const float gt3 = gw2;
        const short4v F0 = mk4(cvt_pk(gt0*silu_f(e0[0]), gt0*silu_f(e0[1])),
                               cvt_pk(gt0*silu_f(e0[2]), gt0*silu_f(e0[3])));
        const short4v F1 = mk4(cvt_pk(gt1*silu_f(e1[0]), gt1*silu_f(e1[1])),
                               cvt_pk(gt1*silu_f(e1[2]), gt1*silu_f(e1[3])));
        const short4v F2 = mk4(cvt_pk(gt2*silu_f(e2[0]), gt2*silu_f(e2[1])),
                               cvt_pk(gt2*silu_f(e2[2]), gt2*silu_f(e2[3])));
        const short4v F3 = (g == 3) ? mk4(cvt_pk(gw0, gw1), cvt_pk(gw2, 0.0f))
                         : mk4(cvt_pk(gt3*silu_f(e3[0]), gt3*silu_f(e3[1])),
                               cvt_pk(gt3*silu_f(e3[2]), gt3*silu_f(e3[3])));
        const short8 AOp0 = WF[12][li], AOp1 = WF[13][li];
        f32x4 co = {0.f,0.f,0.f,0.f};
        co = MFMA16(lo4(AOp0), F0, co); co = MFMA16(hi4(AOp0), F1, co);
        co = MFMA16(lo4(AOp1), F2, co); co = MFMA16(hi4(AOp1), F3, co);
        // co[r] at g==2 = gated+biased moe output o=r; lin lives in c2[r] at g==2

        if (g == 2 && cur + c < B) {
            float* op = out + (size_t)(cur + c) * 3;
            op[0] = c2[0] + co[0];
            op[1] = c2[1] + co[1];
            op[2] = c2[2] + co[2];
        }

        row0 = nrow;
    }
}

extern "C" void kernel_launch(void* const* d_in, const int* in_sizes, int n_in,
                              void* d_out, int out_size, void* d_ws, size_t ws_size,
                              hipStream_t stream) {
    const float* x   = (const float*)d_in[0];
    const float* W1  = (const float*)d_in[1];
    const float* b1  = (const float*)d_in[2];
    const float* lng = (const float*)d_in[3];
    const float* lnb = (const float*)d_in[4];
    const float* W2  = (const float*)d_in[5];
    const float* b2  = (const float*)d_in[6];
    const float* Wg1 = (const float*)d_in[7];
    const float* bg1 = (const float*)d_in[8];
    const float* Wg2 = (const float*)d_in[9];
    const float* bg2 = (const float*)d_in[10];
    const float* We1 = (const float*)d_in[11];
    const float* be1 = (const float*)d_in[12];
    const float* We2 = (const float*)d_in[13];
    const float* be2 = (const float*)d_in[14];
    const float* Wh  = (const float*)d_in[15];
    const float* bh  = (const float*)d_in[16];
    const float* osc = (const float*)d_in[17];
    float* out = (float*)d_out;

    const int B = in_sizes[0] / 64;
    const int G = 1280;                       // 5 blocks/CU = 5 waves/EU resident
    const long long per = (long long)G * 64;  // 64 rows/block/iter
    const int niter = (int)((B + per - 1) / per);
    moe_mfma13_kernel<<<dim3(G), dim3(256), 0, stream>>>(
        x, W1, b1, lng, lnb, W2, b2, Wg1, bg1, Wg2, bg2,
        We1, be1, We2, be2, Wh, bh, osc, out, B, niter);
}

// Round 16
// 69.915 us; speedup vs baseline: 1.2289x; 1.0339x over previous
//
#include <hip/hip_runtime.h>

typedef __attribute__((ext_vector_type(8))) short short8;
typedef __attribute__((ext_vector_type(4))) short short4v;
typedef __attribute__((ext_vector_type(4))) float f32x4;
typedef __attribute__((ext_vector_type(2))) unsigned int uint2v;
typedef __attribute__((ext_vector_type(4))) unsigned int uint4v;

#define LOG2E 1.44269504088896340736f

__device__ __forceinline__ float fexp2(float v){ return __builtin_amdgcn_exp2f(v); }
__device__ __forceinline__ float frcp(float v){ return __builtin_amdgcn_rcpf(v); }
__device__ __forceinline__ float silu_f(float v){ return v * frcp(1.0f + fexp2(-v*LOG2E)); }
__device__ __forceinline__ float tanh_f(float v){ return 2.0f*frcp(1.0f+fexp2(-2.0f*LOG2E*v)) - 1.0f; }

__device__ __forceinline__ unsigned short f2bf(float f){
    unsigned int u = __float_as_uint(f);
    u = (u + 0x7FFFu + ((u>>16)&1u)) >> 16;
    return (unsigned short)u;
}
// v_cvt_pk_bf16_f32: lo16 = bf16(a), hi16 = bf16(b)
__device__ __forceinline__ unsigned int cvt_pk(float a, float b){
    unsigned int r;
    asm("v_cvt_pk_bf16_f32 %0, %1, %2" : "=v"(r) : "v"(a), "v"(b));
    return r;
}
__device__ __forceinline__ short4v mk4(unsigned int u0, unsigned int u1){
    uint2v t; t[0] = u0; t[1] = u1;
    return __builtin_bit_cast(short4v, t);
}
__device__ __forceinline__ short8 mk8(unsigned int a, unsigned int b, unsigned int c, unsigned int d){
    uint4v t; t[0] = a; t[1] = b; t[2] = c; t[3] = d;
    return __builtin_bit_cast(short8, t);
}
__device__ __forceinline__ short8 pack2x4(short4v lo, short4v hi){
    return __builtin_shufflevector(lo, hi, 0,1,2,3,4,5,6,7);
}
__device__ __forceinline__ short4v lo4(short8 v){ return __builtin_shufflevector(v, v, 0,1,2,3); }
__device__ __forceinline__ short4v hi4(short8 v){ return __builtin_shufflevector(v, v, 4,5,6,7); }

#define MFMA32(a,b,c) __builtin_amdgcn_mfma_f32_16x16x32_bf16(a,b,c,0,0,0)
#define MFMA16(a,b,c) __builtin_amdgcn_mfma_f32_16x16x16bf16_1k(a,b,c,0,0,0)

// Fragment layouts (validated rounds 2-15):
//  A frag: m=lane&15,  k = KW*(lane>>4)+e   (KW=8 for x32, 4 for x16)
//  B frag: n=lane&15,  k = KW*(lane>>4)+e
//  C frag: n=lane&15,  m = 4*(lane>>4)+r
// Layout tricks (R9): replicated gate A -> per-lane logits; final GEMM A at
//  m=8..10 -> MoE output lands at g==2 beside lin (stage1 concat f=40..42).
//
// R11-R16 structural rules:
//  - ALL block-uniform lane-dependent state in LDS; per-iteration zoff
//    (opaque zero) defeats LICM re-hoisting into registers (spill trigger).
//  - Occupancy MUST be pinned (min==max): the natural allocator does NOT
//    convert low pressure into waves (R13/R14 flat; R15 (5,5) -> -14%).
//    MIN-hints >=4 on a register-HEAVY body spill (R6/R10); with the
//    LDS-lean body (5,5) was proven clean. (6,6) probes the next step:
//    budget 85 vs honest ~85 — knife-edge by design.
//  - Falsifier: dur >= 80us or WRITE balloon -> revert to (5,5).

__global__ __launch_bounds__(256)
__attribute__((amdgpu_waves_per_eu(6, 6)))
void moe_mfma14_kernel(
    const float* __restrict__ x,
    const float* __restrict__ W1,  const float* __restrict__ b1,
    const float* __restrict__ lng, const float* __restrict__ lnb,
    const float* __restrict__ W2,  const float* __restrict__ b2,
    const float* __restrict__ Wg1, const float* __restrict__ bg1,
    const float* __restrict__ Wg2, const float* __restrict__ bg2,
    const float* __restrict__ We1, const float* __restrict__ be1,
    const float* __restrict__ We2, const float* __restrict__ be2,
    const float* __restrict__ Wh,  const float* __restrict__ bh,
    const float* __restrict__ osc,
    float* __restrict__ out, int B, int niter)
{
    const int tid  = threadIdx.x;
    const int w    = tid >> 6;
    const int lane = tid & 63;
    const int c    = lane & 15;   // batch row within group / A-row m
    const int g    = lane >> 4;   // lane group 0..3

    __shared__ short8 WF[14][64];   // weight fragments, 16B/lane/slot
    __shared__ f32x4  BS[3][64];    // stage1 C-init biases
    __shared__ uint2v AG[64];       // gate A fragment (8B/lane)

    const int stride = (int)gridDim.x * 64;          // 4 waves x 16 rows
    int row0 = (int)blockIdx.x * 64 + w * 16;

    // ---- prefetch iter 0 ----
    f32x4 pf0, pf1, pf2, pf3;
    {
        int r = row0 + c; if (r >= B) r = B - 1; if (r < 0) r = 0;
        const float* xp = x + (size_t)r * 64 + 8 * g;
        pf0 = *(const f32x4*)(xp);
        pf1 = *(const f32x4*)(xp + 4);
        pf2 = *(const f32x4*)(xp + 32);
        pf3 = *(const f32x4*)(xp + 36);
    }

    // ================= wave 0 stages all block-uniform state into LDS =================
    if (w == 0) {
        // stage1 concat features f: [0,24)=W1, [24,40)=Wg1, [40,43)=Wh, pad 48
#pragma unroll
        for (int t = 0; t < 3; ++t) {
            const int f = 16 * t + c;
#pragma unroll
            for (int s = 0; s < 2; ++s) {
                short8 r;
#pragma unroll
                for (int e = 0; e < 8; ++e) {
                    const int k = 32 * s + 8 * g + e;
                    float v = 0.0f;
                    if (f < 24)      v = W1[k * 24 + f];
                    else if (f < 40) v = Wg1[k * 16 + (f - 24)];
                    else if (f < 43) v = Wh[k * 3 + (f - 40)];
                    r[e] = (short)f2bf(v);
                }
                WF[t * 2 + s][lane] = r;
            }
        }
        // W2 (lng folded), K=24 pad 32; b2' (lnb fold) in k==24 slot
#pragma unroll
        for (int t = 0; t < 2; ++t) {
            const int f = 16 * t + c;
            float bfold = 0.0f;
            if (f < 24) {
                bfold = b2[f];
                for (int k = 0; k < 24; ++k) bfold += lnb[k] * W2[k * 24 + f];
            }
            short4v h[2];
#pragma unroll
            for (int s = 0; s < 2; ++s) {
                short4v r;
#pragma unroll
                for (int e = 0; e < 4; ++e) {
                    const int k = 16 * s + 4 * g + e;
                    float v = (f < 24 && k < 24) ? lng[k] * W2[k * 24 + f] : 0.0f;
                    if (s == 1 && g == 2 && e == 0) v = bfold;
                    r[e] = (short)f2bf(v);
                }
                h[s] = r;
            }
            WF[6 + t][lane] = pack2x4(h[0], h[1]);
        }
        // experts hidden concat m in [0,60), K=24 pad 32; be1 in k==24 slot
#pragma unroll
        for (int t = 0; t < 4; ++t) {
            const int f  = 16 * t + c;
            const int fc = (f < 60) ? f : 0;
            const int ei = fc / 20, j = fc % 20;
            const float bias = (f < 60) ? be1[f] : 0.0f;
            short4v h[2];
#pragma unroll
            for (int s = 0; s < 2; ++s) {
                short4v r;
#pragma unroll
                for (int e = 0; e < 4; ++e) {
                    const int k = 16 * s + 4 * g + e;
                    float v = (f < 60 && k < 24) ? We1[(ei * 24 + k) * 20 + j] : 0.0f;
                    if (s == 1 && g == 2 && e == 0) v = bias;
                    r[e] = (short)f2bf(v);
                }
                h[s] = r;
            }
            WF[8 + t][lane] = pack2x4(h[0], h[1]);
        }
        // final GEMM A at rows m=8..10 (o=c-8): We2*osc, be2*osc in k=60..62
        {
            const int  o     = c - 8;
            const bool valid = (c >= 8 && c < 11);
            const int  oc    = valid ? o : 0;
            const float oscv = valid ? osc[oc] : 0.0f;
            short4v h[4];
#pragma unroll
            for (int s = 0; s < 4; ++s) {
                short4v r;
#pragma unroll
                for (int e = 0; e < 4; ++e) {
                    const int k = 16 * s + 4 * g + e;
                    float v = 0.0f;
                    if (valid) {
                        if (k < 60) {
                            const int ei = k / 20, j = k % 20;
                            v = We2[(ei * 20 + j) * 3 + oc] * oscv;
                        } else if (k < 63) {
                            v = be2[(k - 60) * 3 + oc] * oscv;
                        }
                    }
                    r[e] = (short)f2bf(v);
                }
                h[s] = r;
            }
            WF[12][lane] = pack2x4(h[0], h[1]);
            WF[13][lane] = pack2x4(h[2], h[3]);
        }
        // stage1 biases
#pragma unroll
        for (int t = 0; t < 3; ++t) {
            f32x4 bv;
#pragma unroll
            for (int r = 0; r < 4; ++r) {
                const int m = 16 * t + 4 * g + r;
                float v = 0.0f;
                if (m < 24)      v = b1[m];
                else if (m < 40) v = bg1[m - 24];
                else if (m < 43) v = bh[m - 40];
                bv[r] = v;
            }
            BS[t][lane] = bv;
        }
        // gate Wg2 replicated across row-groups: row m holds Wg2[:, m%4]
        {
            const int og = c & 3;
            short4v r;
#pragma unroll
            for (int e = 0; e < 4; ++e) {
                const int k = 4 * g + e;
                float v = (og < 3) ? Wg2[k * 3 + og] : 0.0f;
                r[e] = (short)f2bf(v);
            }
            AG[lane] = __builtin_bit_cast(uint2v, r);
        }
    }

    const float gb0 = bg2[0], gb1 = bg2[1], gb2 = bg2[2];
    const unsigned int ONEBF = 0x00003F80u;  // lo half = bf16(1.0)

    __syncthreads();   // LDS ready; read-only hereafter (no barriers in loop)

    // ================= main loop: one 16-row chain per wave per iter =================
    for (int it = 0; it < niter; ++it) {
        if (row0 >= B) break;

        // opaque zero: LDS addresses become loop-variant -> no LICM re-hoist
        int zoff = 0;
        asm volatile("" : "+v"(zoff));
        const int li = lane + zoff;

        // ---- x -> bf16 B fragments (consumes pf before reloading it) ----
        const short8 bx0 = mk8(cvt_pk(pf0[0],pf0[1]), cvt_pk(pf0[2],pf0[3]),
                               cvt_pk(pf1[0],pf1[1]), cvt_pk(pf1[2],pf1[3]));
        const short8 bx1 = mk8(cvt_pk(pf2[0],pf2[1]), cvt_pk(pf2[2],pf2[3]),
                               cvt_pk(pf3[0],pf3[1]), cvt_pk(pf3[2],pf3[3]));

        const int cur  = row0;
        const int nrow = row0 + stride;
        if (it + 1 < niter && nrow < B) {
            int r = nrow + c; if (r >= B) r = B - 1;
            const float* np = x + (size_t)r * 64 + 8 * g;
            pf0 = *(const f32x4*)(np);
            pf1 = *(const f32x4*)(np + 4);
            pf2 = *(const f32x4*)(np + 32);
            pf3 = *(const f32x4*)(np + 36);
        }

        // ---- stage 1: 3 M-tiles x K=64 (A frags + biases from LDS) ----
        const short8 A100 = WF[0][li], A101 = WF[1][li];
        const short8 A110 = WF[2][li], A111 = WF[3][li];
        const short8 A120 = WF[4][li], A121 = WF[5][li];
        f32x4 c0 = BS[0][li];
        f32x4 c1 = BS[1][li];
        f32x4 c2 = BS[2][li];
        c0 = MFMA32(A100, bx0, c0); c0 = MFMA32(A101, bx1, c0);
        c1 = MFMA32(A110, bx0, c1); c1 = MFMA32(A111, bx1, c1);
        c2 = MFMA32(A120, bx0, c2); c2 = MFMA32(A121, bx1, c2);

        // ---- gate: tanh + lane^32 exchange; replicated-A -> per-lane logits ----
        const f32x4 ts = (g < 2) ? c2 : c1;
        const unsigned int gs0 = cvt_pk(tanh_f(ts[0]), tanh_f(ts[1]));
        const unsigned int gs1 = cvt_pk(tanh_f(ts[2]), tanh_f(ts[3]));
        const unsigned int gr0 = (unsigned int)__shfl_xor((int)gs0, 32, 64);
        const unsigned int gr1 = (unsigned int)__shfl_xor((int)gs1, 32, 64);
        const short4v ag = __builtin_bit_cast(short4v, AG[li]);
        f32x4 cg = { gb0, gb1, gb2, 0.0f };
        cg = MFMA16(ag, mk4(gr0, gr1), cg);

        // ---- silu + LayerNorm (lng/lnb folded into W2 frags) ----
        const float h00=silu_f(c0[0]), h01=silu_f(c0[1]), h02=silu_f(c0[2]), h03=silu_f(c0[3]);
        const float h10=silu_f(c1[0]), h11=silu_f(c1[1]), h12=silu_f(c1[2]), h13=silu_f(c1[3]);
        float S = h00+h01+h02+h03;
        float Q = h00*h00+h01*h01+h02*h02+h03*h03;
        if (g < 2) { S += h10+h11+h12+h13; Q += h10*h10+h11*h11+h12*h12+h13*h13; }
        S += __shfl_xor(S, 16, 64); S += __shfl_xor(S, 32, 64);
        Q += __shfl_xor(Q, 16, 64); Q += __shfl_xor(Q, 32, 64);
        const float mu = S * (1.0f/24.0f);
        float var = Q * (1.0f/24.0f) - mu*mu; var = fmaxf(var, 0.0f);
        const float inv = __builtin_amdgcn_rsqf(var + 1e-5f);

        const short4v B0 = mk4(cvt_pk((h00-mu)*inv, (h01-mu)*inv),
                               cvt_pk((h02-mu)*inv, (h03-mu)*inv));
        const short4v B1 = (g < 2) ? mk4(cvt_pk((h10-mu)*inv, (h11-mu)*inv),
                                         cvt_pk((h12-mu)*inv, (h13-mu)*inv))
                         : ((g == 2) ? mk4(ONEBF, 0u) : mk4(0u, 0u));

        // ---- stage 2 (A frags from LDS; bias rides k==24 slot) ----
        const short8 AWp0 = WF[6][li], AWp1 = WF[7][li];
        f32x4 d0 = {0.f,0.f,0.f,0.f}, d1 = {0.f,0.f,0.f,0.f};
        d0 = MFMA16(lo4(AWp0), B0, d0); d0 = MFMA16(hi4(AWp0), B1, d0);
        d1 = MFMA16(lo4(AWp1), B0, d1); d1 = MFMA16(hi4(AWp1), B1, d1);
        const float j00=silu_f(d0[0]), j01=silu_f(d0[1]), j02=silu_f(d0[2]), j03=silu_f(d0[3]);
        const float j10=silu_f(d1[0]), j11=silu_f(d1[1]), j12=silu_f(d1[2]), j13=silu_f(d1[3]);
        const short4v E0 = mk4(cvt_pk(j00,j01), cvt_pk(j02,j03));
        const short4v E1 = (g < 2) ? mk4(cvt_pk(j10,j11), cvt_pk(j12,j13))
                         : ((g == 2) ? mk4(ONEBF, 0u) : mk4(0u, 0u));

        // ---- experts hidden: 60-feature concat, 4 M-tiles ----
        const short8 AEp0 = WF[8][li],  AEp1 = WF[9][li];
        const short8 AEp2 = WF[10][li], AEp3 = WF[11][li];
        f32x4 e0={0.f,0.f,0.f,0.f}, e1={0.f,0.f,0.f,0.f};
        f32x4 e2={0.f,0.f,0.f,0.f}, e3={0.f,0.f,0.f,0.f};
        e0 = MFMA16(lo4(AEp0), E0, e0); e0 = MFMA16(hi4(AEp0), E1, e0);
        e1 = MFMA16(lo4(AEp1), E0, e1); e1 = MFMA16(hi4(AEp1), E1, e1);
        e2 = MFMA16(lo4(AEp2), E0, e2); e2 = MFMA16(hi4(AEp2), E1, e2);
        e3 = MFMA16(lo4(AEp3), E0, e3); e3 = MFMA16(hi4(AEp3), E1, e3);

        // ---- softmax gate weights (per-lane logits; tanh-bounded, no max-sub) ----
        const float x0 = fexp2(cg[0]*LOG2E), x1 = fexp2(cg[1]*LOG2E), x2 = fexp2(cg[2]*LOG2E);
        const float rs = frcp(x0 + x1 + x2);
        const float gw0 = x0*rs, gw1 = x1*rs, gw2 = x2*rs;

        // ---- final GEMM: B = gw[expert(k)]*silu(eh[k]) (k<60), gw vec in pads ----
        const float gt0 = gw0;
        const float gt1 = (g == 0) ? gw0 : gw1;
        const float gt2 = (g < 2) ? gw1 : gw2;
        const float gt3 = gw2;
        const short4v F0 = mk4(cvt_pk(gt0*silu_f(e0[0]), gt0*silu_f(e0[1])),
                               cvt_pk(gt0*silu_f(e0[2]), gt0*silu_f(e0[3])));
        const short4v F1 = mk4(cvt_pk(gt1*silu_f(e1[0]), gt1*silu_f(e1[1])),
                               cvt_pk(gt1*silu_f(e1[2]), gt1*silu_f(e1[3])));
        const short4v F2 = mk4(cvt_pk(gt2*silu_f(e2[0]), gt2*silu_f(e2[1])),
                               cvt_pk(gt2*silu_f(e2[2]), gt2*silu_f(e2[3])));
        const short4v F3 = (g == 3) ? mk4(cvt_pk(gw0, gw1), cvt_pk(gw2, 0.0f))
                         : mk4(cvt_pk(gt3*silu_f(e3[0]), gt3*silu_f(e3[1])),
                               cvt_pk(gt3*silu_f(e3[2]), gt3*silu_f(e3[3])));
        const short8 AOp0 = WF[12][li], AOp1 = WF[13][li];
        f32x4 co = {0.f,0.f,0.f,0.f};
        co = MFMA16(lo4(AOp0), F0, co); co = MFMA16(hi4(AOp0), F1, co);
        co = MFMA16(lo4(AOp1), F2, co); co = MFMA16(hi4(AOp1), F3, co);
        // co[r] at g==2 = gated+biased moe output o=r; lin lives in c2[r] at g==2

        if (g == 2 && cur + c < B) {
            float* op = out + (size_t)(cur + c) * 3;
            op[0] = c2[0] + co[0];
            op[1] = c2[1] + co[1];
            op[2] = c2[2] + co[2];
        }

        row0 = nrow;
    }
}

extern "C" void kernel_launch(void* const* d_in, const int* in_sizes, int n_in,
                              void* d_out, int out_size, void* d_ws, size_t ws_size,
                              hipStream_t stream) {
    const float* x   = (const float*)d_in[0];
    const float* W1  = (const float*)d_in[1];
    const float* b1  = (const float*)d_in[2];
    const float* lng = (const float*)d_in[3];
    const float* lnb = (const float*)d_in[4];
    const float* W2  = (const float*)d_in[5];
    const float* b2  = (const float*)d_in[6];
    const float* Wg1 = (const float*)d_in[7];
    const float* bg1 = (const float*)d_in[8];
    const float* Wg2 = (const float*)d_in[9];
    const float* bg2 = (const float*)d_in[10];
    const float* We1 = (const float*)d_in[11];
    const float* be1 = (const float*)d_in[12];
    const float* We2 = (const float*)d_in[13];
    const float* be2 = (const float*)d_in[14];
    const float* Wh  = (const float*)d_in[15];
    const float* bh  = (const float*)d_in[16];
    const float* osc = (const float*)d_in[17];
    float* out = (float*)d_out;

    const int B = in_sizes[0] / 64;
    const int G = 1536;                       // 6 blocks/CU = 6 waves/EU resident
    const long long per = (long long)G * 64;  // 64 rows/block/iter
    const int niter = (int)((B + per - 1) / per);
    moe_mfma14_kernel<<<dim3(G), dim3(256), 0, stream>>>(
        x, W1, b1, lng, lnb, W2, b2, Wg1, bg1, Wg2, bg2,
        We1, be1, We2, be2, Wh, bh, osc, out, B, niter);
}